// Round 1
// baseline (40.783 us; speedup 1.0000x reference)
//
#include <hip/hip_runtime.h>
#include <cstddef>

#define BB 2
#define TT 4
#define LL 384
#define CZ 128
#define NBINS 39
#define NBOUND 38

// One block per (b, i). 256 threads.
// LDS: Wd 19.5K + Wj 10.5K + pre 2K + pk 6K + rj 1.5K ~= 39.6 KB -> 4 blocks/CU cap.
__global__ __launch_bounds__(256) void tpe_kernel(
    const int*   __restrict__ aatype,   // [B,T,L] int32
    const float* __restrict__ coords,   // [B,T,L,3] f32
    const int*   __restrict__ tmask,    // [B,T,L] bool->int32
    const int*   __restrict__ rmask,    // [B,L] bool->int32
    const float* __restrict__ weight,   // [82,128] f32
    const float* __restrict__ bias,     // [128] f32
    float*       __restrict__ out)      // [B,L,L,128] f32
{
    __shared__ float Wd_sh[NBINS * CZ];   // rows 0..38
    __shared__ float Wj_sh[21 * CZ];      // rows 61..81
    __shared__ float pre_sh[TT * CZ];     // W_m + W_i[aat_i_t] + bias
    __shared__ int   pk_sh[TT][LL];       // bin | (aat_j<<8), or -1 if masked out
    __shared__ float rj_sh[LL];           // res_pair factor per j

    const int bi  = blockIdx.x;
    const int b   = bi / LL;
    const int i   = bi - b * LL;
    const int tid = threadIdx.x;

    // ---- Phase 1a: stage weight rows into LDS (vectorized) ----
    {
        const float4* wsrc = (const float4*)weight;
        float4* wd = (float4*)Wd_sh;
        #pragma unroll 2
        for (int idx = tid; idx < NBINS * CZ / 4; idx += 256) wd[idx] = wsrc[idx];
        float4* wj = (float4*)Wj_sh;
        for (int idx = tid; idx < 21 * CZ / 4; idx += 256)
            wj[idx] = wsrc[(NBINS + 1 + 21) * CZ / 4 + idx];   // rows 61..81
    }

    // ---- Phase 1b: pre[t][c] = W_m[c] + W_i[aat_i_t][c] + bias[c] ----
    for (int idx = tid; idx < TT * CZ; idx += 256) {
        int t = idx >> 7, c = idx & (CZ - 1);
        int aa = aatype[(b * TT + t) * LL + i];
        aa = min(max(aa, 0), 20);
        pre_sh[idx] = weight[NBINS * CZ + c] + weight[(NBINS + 1 + aa) * CZ + c] + bias[c];
    }

    // ---- Phase 1c: residue-pair factor per j ----
    const int ri = rmask[b * LL + i];
    for (int j = tid; j < LL; j += 256)
        rj_sh[j] = (ri != 0 && rmask[b * LL + j] != 0) ? 1.0f : 0.0f;

    // ---- Phase 1d: distance bins + aat_j, packed. Bit-exact vs numpy f32:
    //      no FP contraction; boundaries = f32(3.25 + k*(47.5/37) in f64). ----
    {
        #pragma clang fp contract(off)
        for (int idx = tid; idx < TT * LL; idx += 256) {
            int t = idx / LL, j = idx - t * LL;
            const int base = (b * TT + t) * LL;
            int pk = -1;
            if (tmask[base + i] != 0 && tmask[base + j] != 0) {
                const float* ci = coords + (size_t)(base + i) * 3;
                const float* cj = coords + (size_t)(base + j) * 3;
                float dx = ci[0] - cj[0];
                float dy = ci[1] - cj[1];
                float dz = ci[2] - cj[2];
                float s  = dx * dx + dy * dy;   // numpy sum order: ((x+y)+z)
                s = s + dz * dz;
                float d = sqrtf(s);             // IEEE sqrt (no fast-math)
                int bin = 0;
                #pragma unroll
                for (int k = 0; k < NBOUND; ++k) {
                    // compile-time folded, matches np.linspace(f64).astype(f32)
                    float bnd = (float)(3.25 + (double)k * (47.5 / 37.0));
                    bin += (d > bnd) ? 1 : 0;   // count boundaries < d (side='left')
                }
                int aa = aatype[base + j];
                aa = min(max(aa, 0), 20);
                pk = bin | (aa << 8);
            }
            pk_sh[t][j] = pk;
        }
    }
    __syncthreads();

    // ---- Phase 2: 32 threads x float4 cover 128 channels; 8 j in flight ----
    const int cg = tid & 31;       // channel group (4 channels)
    const int jj = tid >> 5;       // 0..7
    const float4* Wd4  = (const float4*)Wd_sh;
    const float4* Wj4  = (const float4*)Wj_sh;
    const float4* pre4 = (const float4*)pre_sh;
    float4* outv = (float4*)(out + (size_t)(b * LL + i) * LL * CZ);

    for (int j = jj; j < LL; j += 8) {
        int cnt = 0;
        float4 acc = {0.0f, 0.0f, 0.0f, 0.0f};
        #pragma unroll
        for (int t = 0; t < TT; ++t) {
            int pk = pk_sh[t][j];
            if (pk >= 0) {
                ++cnt;
                float4 wd = Wd4[(pk & 255) * (CZ / 4) + cg];
                float4 wj = Wj4[(pk >> 8) * (CZ / 4) + cg];
                float4 pr = pre4[t * (CZ / 4) + cg];
                acc.x += wd.x + wj.x + pr.x;
                acc.y += wd.y + wj.y + pr.y;
                acc.z += wd.z + wj.z + pr.z;
                acc.w += wd.w + wj.w + pr.w;
            }
        }
        float inv = rj_sh[j] / fmaxf((float)cnt, 1.0f);
        float4 o;
        o.x = acc.x * inv; o.y = acc.y * inv; o.z = acc.z * inv; o.w = acc.w * inv;
        outv[j * (CZ / 4) + cg] = o;
    }
}

extern "C" void kernel_launch(void* const* d_in, const int* in_sizes, int n_in,
                              void* d_out, int out_size, void* d_ws, size_t ws_size,
                              hipStream_t stream) {
    const int*   aatype = (const int*)d_in[0];
    const float* coords = (const float*)d_in[1];
    const int*   tmask  = (const int*)d_in[2];
    const int*   rmask  = (const int*)d_in[3];
    const float* weight = (const float*)d_in[4];
    const float* bias   = (const float*)d_in[5];
    float* out = (float*)d_out;

    dim3 grid(BB * LL);
    dim3 block(256);
    tpe_kernel<<<grid, block, 0, stream>>>(aatype, coords, tmask, rmask, weight, bias, out);
}

// Round 2
// 34.019 us; speedup vs baseline: 1.1988x; 1.1988x over previous
//
#include <hip/hip_runtime.h>
#include <cstddef>

#define BB 2
#define TT 4
#define LL 384
#define CZ 128
#define NBINS 39
#define NBOUND 38

// One block per (b, i). 512 threads.
// LDS: Wd 19.5K + Wj 10.5K + presum 8K + meta 6K = 44 KB -> 3 blocks/CU.
__global__ __launch_bounds__(512) void tpe_kernel(
    const int*   __restrict__ aatype,   // [B,T,L] int32
    const float* __restrict__ coords,   // [B,T,L,3] f32
    const int*   __restrict__ tmask,    // [B,T,L] bool->int32
    const int*   __restrict__ rmask,    // [B,L] bool->int32
    const float* __restrict__ weight,   // [82,128] f32
    const float* __restrict__ bias,     // [128] f32
    float*       __restrict__ out)      // [B,L,L,128] f32
{
    __shared__ float Wd_sh[NBINS * CZ];   // weight rows 0..38
    __shared__ float Wj_sh[21 * CZ];      // weight rows 61..81
    __shared__ float ps_sh[16 * CZ];      // subset sums of (W_m + W_i[aat_i_t] + bias)
    __shared__ int4  meta_sh[LL];         // {pk01, pk23, code, scale_bits}

    const int bi  = blockIdx.x;
    const int b   = bi / LL;
    const int i   = bi - b * LL;
    const int tid = threadIdx.x;

    // ---- Phase 1a: stage Wd / Wj rows into LDS (vectorized) ----
    {
        const float4* wsrc = (const float4*)weight;
        float4* wd = (float4*)Wd_sh;
        for (int idx = tid; idx < NBINS * CZ / 4; idx += 512) wd[idx] = wsrc[idx];
        float4* wj = (float4*)Wj_sh;
        for (int idx = tid; idx < 21 * CZ / 4; idx += 512)
            wj[idx] = wsrc[(NBINS + 1 + 21) * CZ / 4 + idx];   // rows 61..81
    }

    // ---- Phase 1b: presum[code][c] = sum over t in code of (W_m + W_i[aat_i_t] + bias) ----
    for (int idx = tid; idx < 16 * CZ; idx += 512) {
        int code = idx >> 7, c = idx & (CZ - 1);
        float v = 0.0f;
        if (code) {
            float base = weight[NBINS * CZ + c] + bias[c];   // W_m + bias
            v = (float)__popc(code) * base;
            #pragma unroll
            for (int t = 0; t < TT; ++t) {
                if (code & (1 << t)) {
                    int aa = aatype[(b * TT + t) * LL + i];
                    aa = min(max(aa, 0), 20);
                    v += weight[(NBINS + 1 + aa) * CZ + c];
                }
            }
        }
        ps_sh[idx] = v;
    }

    // ---- Phase 1c: per-j metadata: packed bins/aat, active code, final scale ----
    {
        #pragma clang fp contract(off)
        const int ri = rmask[b * LL + i];
        for (int j = tid; j < LL; j += 512) {
            unsigned pk01 = 0, pk23 = 0;
            int code = 0;
            #pragma unroll
            for (int t = 0; t < TT; ++t) {
                const int base = (b * TT + t) * LL;
                unsigned pk = 0xFFFFu;
                if (tmask[base + i] != 0 && tmask[base + j] != 0) {
                    const float* ci = coords + (size_t)(base + i) * 3;
                    const float* cj = coords + (size_t)(base + j) * 3;
                    float dx = ci[0] - cj[0];
                    float dy = ci[1] - cj[1];
                    float dz = ci[2] - cj[2];
                    float s  = dx * dx + dy * dy;    // numpy order: ((x+y)+z)
                    s = s + dz * dz;
                    float d = sqrtf(s);              // IEEE sqrt
                    int bin = 0;
                    #pragma unroll
                    for (int k = 0; k < NBOUND; ++k) {
                        float bnd = (float)(3.25 + (double)k * (47.5 / 37.0));
                        bin += (d > bnd) ? 1 : 0;    // searchsorted side='left'
                    }
                    int aa = aatype[base + j];
                    aa = min(max(aa, 0), 20);
                    pk = (unsigned)(bin | (aa << 6));
                    code |= (1 << t);
                }
                if (t < 2) pk01 |= pk << (16 * t);
                else       pk23 |= pk << (16 * (t - 2));
            }
            int cnt = __popc(code);
            float scale = (ri != 0 && rmask[b * LL + j] != 0)
                          ? 1.0f / fmaxf((float)cnt, 1.0f) : 0.0f;
            int4 m;
            m.x = (int)pk01; m.y = (int)pk23; m.z = code; m.w = __float_as_int(scale);
            meta_sh[j] = m;
        }
    }
    __syncthreads();

    // ---- Phase 2: 32 lanes x float4 = 128 channels; 16 j-slots in flight ----
    const int cg = tid & 31;       // channel group (4 channels)
    const int jj = tid >> 5;       // 0..15
    const float4* Wd4 = (const float4*)Wd_sh;
    const float4* Wj4 = (const float4*)Wj_sh;
    const float4* ps4 = (const float4*)ps_sh;
    float4* outv = (float4*)(out + (size_t)(b * LL + i) * LL * CZ);

    #pragma unroll 2
    for (int j = jj; j < LL; j += 16) {
        int4 m = meta_sh[j];                       // broadcast b128
        const int code = m.z;
        const float scale = __int_as_float(m.w);
        float4 acc = ps4[code * (CZ / 4) + cg];    // subset-sum init
        const unsigned pk01 = (unsigned)m.x, pk23 = (unsigned)m.y;

        if (code & 1) {
            unsigned pk = pk01 & 0xFFFFu;
            float4 a = Wd4[(pk & 63u) * (CZ / 4) + cg];
            float4 c2 = Wj4[(pk >> 6) * (CZ / 4) + cg];
            acc.x += a.x + c2.x; acc.y += a.y + c2.y; acc.z += a.z + c2.z; acc.w += a.w + c2.w;
        }
        if (code & 2) {
            unsigned pk = pk01 >> 16;
            float4 a = Wd4[(pk & 63u) * (CZ / 4) + cg];
            float4 c2 = Wj4[(pk >> 6) * (CZ / 4) + cg];
            acc.x += a.x + c2.x; acc.y += a.y + c2.y; acc.z += a.z + c2.z; acc.w += a.w + c2.w;
        }
        if (code & 4) {
            unsigned pk = pk23 & 0xFFFFu;
            float4 a = Wd4[(pk & 63u) * (CZ / 4) + cg];
            float4 c2 = Wj4[(pk >> 6) * (CZ / 4) + cg];
            acc.x += a.x + c2.x; acc.y += a.y + c2.y; acc.z += a.z + c2.z; acc.w += a.w + c2.w;
        }
        if (code & 8) {
            unsigned pk = pk23 >> 16;
            float4 a = Wd4[(pk & 63u) * (CZ / 4) + cg];
            float4 c2 = Wj4[(pk >> 6) * (CZ / 4) + cg];
            acc.x += a.x + c2.x; acc.y += a.y + c2.y; acc.z += a.z + c2.z; acc.w += a.w + c2.w;
        }
        float4 o;
        o.x = acc.x * scale; o.y = acc.y * scale;
        o.z = acc.z * scale; o.w = acc.w * scale;
        outv[j * (CZ / 4) + cg] = o;
    }
}

extern "C" void kernel_launch(void* const* d_in, const int* in_sizes, int n_in,
                              void* d_out, int out_size, void* d_ws, size_t ws_size,
                              hipStream_t stream) {
    const int*   aatype = (const int*)d_in[0];
    const float* coords = (const float*)d_in[1];
    const int*   tmask  = (const int*)d_in[2];
    const int*   rmask  = (const int*)d_in[3];
    const float* weight = (const float*)d_in[4];
    const float* bias   = (const float*)d_in[5];
    float* out = (float*)d_out;

    dim3 grid(BB * LL);
    dim3 block(512);
    tpe_kernel<<<grid, block, 0, stream>>>(aatype, coords, tmask, rmask, weight, bias, out);
}